// Round 4
// baseline (491.644 us; speedup 1.0000x reference)
//
#include <hip/hip_runtime.h>
#include <stdint.h>

// ---------------------------------------------------------------------------
// Attention_global: B=8,C=48,H=W=256,HEADS=8,FCT=16 -> per (b,head): N=256
// tokens (n=fx*16+fy), d=1536 (d=c*256+h*16+w), c=6.
// R10: k_dw = R9 geometry (128-wide tile, cl-loop, granule-XOR LDS, one
// contiguous uint4 store per thread per ch) MINUS v_pk_fma asm (spill source;
// back to scalar fmaf like R8) PLUS __launch_bounds__(256,4) VGPR headroom.
// Norms fused in k_sgemm (R8, proven). ws peak = 302,120,960 B.
// ---------------------------------------------------------------------------

#define DI __device__ __forceinline__
typedef __attribute__((ext_vector_type(8))) short short8;
typedef __attribute__((ext_vector_type(4))) float f32x4;

DI unsigned short f2bf(float f){
  unsigned u = __float_as_uint(f);
  unsigned r = (u + 0x7FFFu + ((u >> 16) & 1u)) >> 16;
  return (unsigned short)r;
}
DI float bf2f(unsigned short h){ return __uint_as_float(((unsigned)h) << 16); }

// ---------------------------------------------------------------------------
// K1a: qkv[b][o][p] = sum_c wq[o][c] * x[b][c][p], o in [0,144).
// MFMA M=144,K=48(pad 64),N=128 px/block. grid 4096.
// ---------------------------------------------------------------------------
__global__ __launch_bounds__(256) void k_qkv(const float* __restrict__ x,
                                             const float* __restrict__ wq,
                                             unsigned short* __restrict__ qkv)
{
  __shared__ unsigned short sm[19584]; // A[144][72]@0 + B[128][72]@10368; reuse D[144][136]
  unsigned short* const lA = sm;
  unsigned short* const lB = sm + 10368;
  const int t = threadIdx.x;
  const int g0 = blockIdx.x << 7;
  const int b  = g0 >> 16;
  const int p0 = g0 & 65535;

  for (int i = t; i < 9792; i += 256) ((unsigned*)sm)[i] = 0u; // k-pad must be 0
  __syncthreads();
  for (int j = t; j < 6912; j += 256){
    int m = j / 48, k = j - m * 48;
    lA[m * 72 + k] = f2bf(wq[j]);
  }
  // B = x^T tile [pixel][k=c]: bf16-pair pack + XOR block swizzle
  for (int j = t; j < 384; j += 256){
    int cp = j >> 4, nc = j & 15;
    const float* xr = x + ((size_t)(b * 48 + 2 * cp)) * 65536 + p0 + nc * 8;
    float4 a0 = *(const float4*)xr;
    float4 a1 = *(const float4*)(xr + 4);
    float4 b0 = *(const float4*)(xr + 65536);
    float4 b1 = *(const float4*)(xr + 65536 + 4);
    float r0[8] = {a0.x,a0.y,a0.z,a0.w,a1.x,a1.y,a1.z,a1.w};
    float r1[8] = {b0.x,b0.y,b0.z,b0.w,b1.x,b1.y,b1.z,b1.w};
    unsigned* dst = (unsigned*)lB;
    int cx = (nc & 7) << 2;
    #pragma unroll
    for (int i = 0; i < 8; i++)
      dst[(nc * 8 + i) * 36 + (cp ^ cx)] =
        (unsigned)f2bf(r0[i]) | ((unsigned)f2bf(r1[i]) << 16);
  }
  __syncthreads();

  const int lane = t & 63, wv = t >> 6;
  const int m15 = lane & 15, quad = lane >> 4;
  const int nw = wv << 5;
  f32x4 acc[9][2];
  f32x4 z = {0.f,0.f,0.f,0.f};
  #pragma unroll
  for (int i = 0; i < 9; i++){ acc[i][0] = z; acc[i][1] = z; }

  #pragma unroll
  for (int ks = 0; ks < 2; ks++){
    short8 bfr[2];
    #pragma unroll
    for (int nt = 0; nt < 2; nt++){
      int row = nw + nt * 16 + m15;
      bfr[nt] = *(const short8*)(lB + row * 72 + (((4 * ks + quad) ^ ((row >> 3) & 7)) << 3));
    }
    #pragma unroll
    for (int mt = 0; mt < 9; mt++){
      short8 afr = *(const short8*)(lA + (mt * 16 + m15) * 72 + ks * 32 + quad * 8);
      acc[mt][0] = __builtin_amdgcn_mfma_f32_16x16x32_bf16(afr, bfr[0], acc[mt][0], 0, 0, 0);
      acc[mt][1] = __builtin_amdgcn_mfma_f32_16x16x32_bf16(afr, bfr[1], acc[mt][1], 0, 0, 0);
    }
  }
  __syncthreads();
  #pragma unroll
  for (int mt = 0; mt < 9; mt++)
    #pragma unroll
    for (int nt = 0; nt < 2; nt++)
      #pragma unroll
      for (int r = 0; r < 4; r++)
        sm[(mt * 16 + quad * 4 + r) * 136 + nw + nt * 16 + m15] = f2bf(acc[mt][nt][r]);
  __syncthreads();
  for (int j = t; j < 2304; j += 256){
    int o = j >> 4, oc = j & 15;
    *(uint4*)(qkv + ((size_t)(b * 144 + o)) * 65536 + p0 + oc * 8) =
      *(const uint4*)(sm + o * 136 + oc * 8);
  }
}

// ---------------------------------------------------------------------------
// K1b: depthwise 3x3 (SAME) over qkv (144 ch); writes Q/K/V tokens bf16.
// grid (2, 16, 8*72): z = b*72+cg, ch0=2cg; block = 128 cols x 16 rows,
// 2 ch via cl-loop. LDS column-major [cl][130 cols][32 slots], granule-XOR
// slot = ((gr ^ ((cx>>1)&3))<<3)+rl. Thread = (x = t>>1, yg = t&1):
// 8 consecutive fy -> one uint4 store per ch (wave store = contiguous 1KB).
// Scalar fmaf taps (no packed-math asm: avoids regalloc damage / spills).
// ---------------------------------------------------------------------------
__global__ __launch_bounds__(256, 4) void k_dw(const unsigned short* __restrict__ qkv,
                                               const float* __restrict__ wd,
                                               unsigned short* __restrict__ tok0)
{
  __shared__ unsigned short tile[2][4160];   // 2 x 130 x 32 = 16640B
  const int t = threadIdx.x;
  const int wgx = blockIdx.x, hb = blockIdx.y;
  const int b = blockIdx.z / 72, cg = blockIdx.z % 72;
  const int ch0 = cg * 2;
  const int y0 = hb << 4, xg = wgx << 7;

  // interior staging: 2ch x 18 rows x 16 segs of 8px; rotated scalar writes
  for (int j = t; j < 576; j += 256){
    int rowch = j >> 4, seg = j & 15;
    int cl = rowch >= 18, row = rowch - cl * 18;
    int y = y0 - 1 + row;
    uint4 v = {0u,0u,0u,0u};
    if ((unsigned)y < 256u)
      v = *(const uint4*)(qkv + ((size_t)(b*144 + ch0 + cl))*65536 + y*256 + xg + seg*8);
    const unsigned short* u = (const unsigned short*)&v;
    int gr = row >> 3, rl = row & 7;
    #pragma unroll
    for (int i = 0; i < 8; i++){
      int ii = (i + seg) & 7;
      int cx = seg * 8 + ii + 1;
      tile[cl][cx * 32 + ((gr ^ ((cx >> 1) & 3)) << 3) + rl] = u[ii];
    }
  }
  // halo cols: global x = xg-1 -> cx 0, x = xg+128 -> cx 129
  if (t < 72){
    int rowch = t >> 1, side = t & 1;
    int cl = rowch >= 18, row = rowch - cl * 18;
    int y = y0 - 1 + row;
    int xx = side ? (xg + 128) : (xg - 1);
    unsigned short v = 0;
    if ((unsigned)y < 256u && (unsigned)xx < 256u)
      v = qkv[((size_t)(b*144 + ch0 + cl))*65536 + y*256 + xx];
    int cx = side ? 129 : 0;
    tile[cl][cx * 32 + (((row >> 3) ^ ((cx >> 1) & 3)) << 3) + (row & 7)] = v;
  }
  __syncthreads();

  const int x = t >> 1, yg = t & 1;
  const int fx = x & 15, wp = wgx * 8 + (x >> 4);
  #pragma unroll
  for (int cl = 0; cl < 2; cl++){
    const int ch = ch0 + cl;
    float w9[9];
    #pragma unroll
    for (int i = 0; i < 9; i++) w9[i] = wd[ch * 9 + i];   // wave-uniform
    float o[8] = {0.f,0.f,0.f,0.f,0.f,0.f,0.f,0.f};
    #pragma unroll
    for (int dx = 0; dx < 3; dx++){
      int cx = x + dx;                         // global cols x-1 .. x+1
      const unsigned short* cb = tile[cl] + cx * 32;
      int sw = (cx >> 1) & 3;
      uint4 va = *(const uint4*)(cb + ((yg ^ sw) << 3));              // rows yg*8+0..7
      unsigned vc = *(const unsigned*)(cb + (((yg + 1) ^ sw) << 3));  // rows yg*8+8,9
      float fv[10];
      fv[0] = __uint_as_float(va.x << 16);
      fv[1] = __uint_as_float(va.x & 0xffff0000u);
      fv[2] = __uint_as_float(va.y << 16);
      fv[3] = __uint_as_float(va.y & 0xffff0000u);
      fv[4] = __uint_as_float(va.z << 16);
      fv[5] = __uint_as_float(va.z & 0xffff0000u);
      fv[6] = __uint_as_float(va.w << 16);
      fv[7] = __uint_as_float(va.w & 0xffff0000u);
      fv[8] = __uint_as_float(vc << 16);
      fv[9] = __uint_as_float(vc & 0xffff0000u);
      #pragma unroll
      for (int r = 0; r < 8; r++)
        o[r] = fmaf(fv[r],     w9[dx],
               fmaf(fv[r + 1], w9[3 + dx],
               fmaf(fv[r + 2], w9[6 + dx], o[r])));
    }
    // one contiguous 16B store: n = fx*16 + yg*8 + (0..7)
    const int split = ch / 48;
    const int chs = ch - split * 48;
    const int head = chs / 6, ccb = chs - head * 6;
    uint4 pk;
    asm("v_cvt_pk_bf16_f32 %0, %1, %2" : "=v"(pk.x) : "v"(o[0]), "v"(o[1]));
    asm("v_cvt_pk_bf16_f32 %0, %1, %2" : "=v"(pk.y) : "v"(o[2]), "v"(o[3]));
    asm("v_cvt_pk_bf16_f32 %0, %1, %2" : "=v"(pk.z) : "v"(o[4]), "v"(o[5]));
    asm("v_cvt_pk_bf16_f32 %0, %1, %2" : "=v"(pk.w) : "v"(o[6]), "v"(o[7]));
    *(uint4*)(tok0 + (size_t)split * 25165824
              + ((size_t)(b * 8 + head)) * 393216
              + ((size_t)(ccb * 256 + hb * 16 + wp)) * 256 + fx * 16 + yg * 8) = pk;
  }
}

// ---------------------------------------------------------------------------
// K3: S[bh][n][m] = sum_d Q[bh][d][n]*K[bh][d][m]. 128x128/block, grid (4,64).
// Fused l2-norm sums (R8, proven): m0==0 blocks sum Q^2 per n, n0==0 blocks
// sum K^2 per m; shfl+LDS reduce, direct write (no atomics).
// ---------------------------------------------------------------------------
__global__ __launch_bounds__(256) void k_sgemm(const unsigned short* __restrict__ Qd,
                                               const unsigned short* __restrict__ Kd,
                                               float* __restrict__ S,
                                               float* __restrict__ nrm)
{
  __shared__ unsigned short sm[18432];
  unsigned short* const sa = sm;
  unsigned short* const sb = sm + 9216;
  const int t = threadIdx.x;
  const int bh = blockIdx.y;
  const int n0 = (blockIdx.x >> 1) << 7;
  const int m0 = (blockIdx.x & 1) << 7;
  const int lane = t & 63, wv = t >> 6;
  const int m15 = lane & 15, quad = lane >> 4;
  const int wm = (wv & 1) << 6, wn = (wv >> 1) << 6;
  const size_t base = (size_t)bh * 393216;
  f32x4 acc[4][4];
  f32x4 z = {0.f,0.f,0.f,0.f};
  #pragma unroll
  for (int i = 0; i < 4; i++)
    #pragma unroll
    for (int j = 0; j < 4; j++) acc[i][j] = z;
  float aq[8] = {0.f,0.f,0.f,0.f,0.f,0.f,0.f,0.f};
  float ak[8] = {0.f,0.f,0.f,0.f,0.f,0.f,0.f,0.f};

  const int kpb = t >> 4, nc = t & 15;
  const int cxs = (nc & 7) << 2;
  for (int s = 0; s < 24; s++){
    __syncthreads();
    #pragma unroll
    for (int kk = 0; kk < 2; kk++){
      int kp = kpb + kk * 16;
      const unsigned short* srcq = Qd + base + (size_t)(s * 64 + 2 * kp) * 256 + n0 + nc * 8;
      uint4 q0 = *(const uint4*)srcq;
      uint4 q1 = *(const uint4*)(srcq + 256);
      const unsigned short* u0 = (const unsigned short*)&q0;
      const unsigned short* u1 = (const unsigned short*)&q1;
      unsigned* dsta = (unsigned*)sa;
      #pragma unroll
      for (int i = 0; i < 8; i++){
        dsta[(nc * 8 + i) * 36 + (kp ^ cxs)] = (unsigned)u0[i] | ((unsigned)u1[i] << 16);
        if (m0 == 0){
          float f0 = bf2f(u0[i]), f1 = bf2f(u1[i]);
          aq[i] = fmaf(f0, f0, fmaf(f1, f1, aq[i]));
        }
      }
      const unsigned short* srck = Kd + base + (size_t)(s * 64 + 2 * kp) * 256 + m0 + nc * 8;
      uint4 k0 = *(const uint4*)srck;
      uint4 k1 = *(const uint4*)(srck + 256);
      const unsigned short* v0 = (const unsigned short*)&k0;
      const unsigned short* v1 = (const unsigned short*)&k1;
      unsigned* dstb = (unsigned*)sb;
      #pragma unroll
      for (int i = 0; i < 8; i++){
        dstb[(nc * 8 + i) * 36 + (kp ^ cxs)] = (unsigned)v0[i] | ((unsigned)v1[i] << 16);
        if (n0 == 0){
          float f0 = bf2f(v0[i]), f1 = bf2f(v1[i]);
          ak[i] = fmaf(f0, f0, fmaf(f1, f1, ak[i]));
        }
      }
    }
    __syncthreads();
    #pragma unroll
    for (int ks = 0; ks < 2; ks++){
      short8 afr[4], bfr[4];
      #pragma unroll
      for (int i = 0; i < 4; i++){
        int ra = wm + i * 16 + m15;
        int rb = wn + i * 16 + m15;
        afr[i] = *(const short8*)(sa + ra * 72 + (((4 * ks + quad) ^ ((ra >> 3) & 7)) << 3));
        bfr[i] = *(const short8*)(sb + rb * 72 + (((4 * ks + quad) ^ ((rb >> 3) & 7)) << 3));
      }
      #pragma unroll
      for (int mi = 0; mi < 4; mi++)
        #pragma unroll
        for (int ni = 0; ni < 4; ni++)
          acc[mi][ni] = __builtin_amdgcn_mfma_f32_16x16x32_bf16(afr[mi], bfr[ni], acc[mi][ni], 0, 0, 0);
    }
  }

  // fused norm reduce: in-wave over kp (^16,^32), cross-wave via LDS
  __syncthreads();
  float* nb = (float*)sm;                 // 1024 floats (within sa region)
  #pragma unroll
  for (int i = 0; i < 8; i++){
    aq[i] += __shfl_xor(aq[i], 16); aq[i] += __shfl_xor(aq[i], 32);
    ak[i] += __shfl_xor(ak[i], 16); ak[i] += __shfl_xor(ak[i], 32);
  }
  if (lane < 16){
    #pragma unroll
    for (int i = 0; i < 8; i++){
      nb[wv * 128 + m15 * 8 + i]       = aq[i];
      nb[512 + wv * 128 + m15 * 8 + i] = ak[i];
    }
  }
  __syncthreads();
  if (m0 == 0 && t < 128)
    nrm[(size_t)bh * 256 + n0 + t] = nb[t] + nb[128 + t] + nb[256 + t] + nb[384 + t];
  if (n0 == 0 && t >= 128){
    int m = t - 128;
    nrm[16384 + (size_t)bh * 256 + m0 + m] =
      nb[512 + m] + nb[640 + m] + nb[768 + m] + nb[896 + m];
  }

  #pragma unroll
  for (int mi = 0; mi < 4; mi++)
    #pragma unroll
    for (int ni = 0; ni < 4; ni++)
      #pragma unroll
      for (int r = 0; r < 4; r++){
        int nr = n0 + wm + mi * 16 + quad * 4 + r;
        int mc = m0 + wn + ni * 16 + m15;
        S[(size_t)bh * 65536 + (size_t)nr * 256 + mc] = acc[mi][ni][r];
      }
}

// ---------------------------------------------------------------------------
// K4: softmax_1 with l2-norm scaling + temperature (reads fused norms).
// ---------------------------------------------------------------------------
__global__ __launch_bounds__(256) void k_softmax(const float* __restrict__ S,
                                                 const float* __restrict__ nrm,
                                                 const float* __restrict__ temp,
                                                 unsigned short* __restrict__ P)
{
  const int t = threadIdx.x, lane = t & 63, wv = t >> 6;
  const int bh = blockIdx.y;
  const int n = blockIdx.x * 4 + wv;
  const float tp = temp[bh & 7];
  const size_t ro = (size_t)bh * 65536 + (size_t)n * 256;
  float4 sv = *(const float4*)(S + ro + lane * 4);
  float4 ka = *(const float4*)(nrm + 16384 + (size_t)bh * 256 + lane * 4);
  float nqv = nrm[(size_t)bh * 256 + n];
  float qi = tp / fmaxf(sqrtf(fmaxf(nqv, 0.f)), 1e-12f);
  float i0 = 1.f / fmaxf(sqrtf(fmaxf(ka.x, 0.f)), 1e-12f);
  float i1 = 1.f / fmaxf(sqrtf(fmaxf(ka.y, 0.f)), 1e-12f);
  float i2 = 1.f / fmaxf(sqrtf(fmaxf(ka.z, 0.f)), 1e-12f);
  float i3 = 1.f / fmaxf(sqrtf(fmaxf(ka.w, 0.f)), 1e-12f);
  float e0 = __expf(fminf(sv.x * qi * i0, 60.f));
  float e1 = __expf(fminf(sv.y * qi * i1, 60.f));
  float e2 = __expf(fminf(sv.z * qi * i2, 60.f));
  float e3 = __expf(fminf(sv.w * qi * i3, 60.f));
  float ss = e0 + e1 + e2 + e3;
  #pragma unroll
  for (int o = 32; o > 0; o >>= 1) ss += __shfl_xor(ss, o);
  float inv = 1.f / (ss + 1.f);
  uint2 pv;
  pv.x = (unsigned)f2bf(e0 * inv) | ((unsigned)f2bf(e1 * inv) << 16);
  pv.y = (unsigned)f2bf(e2 * inv) | ((unsigned)f2bf(e3 * inv) << 16);
  *(uint2*)(P + ro + lane * 4) = pv;
}

// ---------------------------------------------------------------------------
// K5: O[bh][d][n] = sum_m V[bh][d][m] * P[bh][n][m]. 128x128/block, grid(24,64).
// ---------------------------------------------------------------------------
__global__ __launch_bounds__(256) void k_ogemm(const unsigned short* __restrict__ Vd,
                                               const unsigned short* __restrict__ P,
                                               unsigned short* __restrict__ Od)
{
  __shared__ unsigned short sm[18432];
  unsigned short* const sa = sm;
  unsigned short* const sb = sm + 9216;
  const int t = threadIdx.x;
  const int bh = blockIdx.y;
  const int d0 = (blockIdx.x >> 1) << 7;
  const int n0 = (blockIdx.x & 1) << 7;
  const int lane = t & 63, wv = t >> 6;
  const int m15 = lane & 15, quad = lane >> 4;
  const int wm = (wv & 1) << 6, wn = (wv >> 1) << 6;
  f32x4 acc[4][4];
  f32x4 z = {0.f,0.f,0.f,0.f};
  #pragma unroll
  for (int i = 0; i < 4; i++)
    #pragma unroll
    for (int j = 0; j < 4; j++) acc[i][j] = z;

  for (int s = 0; s < 4; s++){
    __syncthreads();
    for (int j = t; j < 512; j += 256){
      int hf = j >> 8, jj = j & 255;
      int row = jj >> 1, hh = jj & 1;
      const unsigned short* src = hf
        ? (P  + (size_t)bh * 65536  + (size_t)(n0 + row) * 256 + s * 64 + hh * 32)
        : (Vd + (size_t)bh * 393216 + (size_t)(d0 + row) * 256 + s * 64 + hh * 32);
      uint4 v0 = *(const uint4*)src;
      uint4 v1 = *(const uint4*)(src + 8);
      uint4 v2 = *(const uint4*)(src + 16);
      uint4 v3 = *(const uint4*)(src + 24);
      unsigned* dst = (unsigned*)(hf ? sb : sa) + row * 36 + hh * 16;
      *(uint4*)dst        = v0;
      *(uint4*)(dst + 4)  = v1;
      *(uint4*)(dst + 8)  = v2;
      *(uint4*)(dst + 12) = v3;
    }
    __syncthreads();
    #pragma unroll
    for (int ks = 0; ks < 2; ks++){
      short8 afr[4], bfr[4];
      #pragma unroll
      for (int i = 0; i < 4; i++){
        afr[i] = *(const short8*)(sa + (wm + i * 16 + m15) * 72 + ks * 32 + quad * 8);
        bfr[i] = *(const short8*)(sb + (wn + i * 16 + m15) * 72 + ks * 32 + quad * 8);
      }
      #pragma unroll
      for (int mi = 0; mi < 4; mi++)
        #pragma unroll
        for (int ni = 0; ni < 4; ni++)
          acc[mi][ni] = __builtin_amdgcn_mfma_f32_16x16x32_bf16(afr[mi], bfr[ni], acc[mi][ni], 0, 0, 0);
    }
  }
  __syncthreads();
  #pragma unroll
  for (int mi = 0; mi < 4; mi++)
    #pragma unroll
    for (int ni = 0; ni < 4; ni++)
      #pragma unroll
      for (int r = 0; r < 4; r++)
        sm[(wm + mi * 16 + quad * 4 + r) * 136 + wn + ni * 16 + m15] = f2bf(acc[mi][ni][r]);
  __syncthreads();
  {
    int row = t >> 1, hh = t & 1;
    const unsigned short* lp = sm + row * 136 + hh * 64;
    unsigned short* gp = Od + (size_t)bh * 393216 + (size_t)(d0 + row) * 256 + n0 + hh * 64;
    #pragma unroll
    for (int u = 0; u < 8; u++)
      *(uint4*)(gp + u * 8) = *(const uint4*)(lp + u * 8);
  }
}

// ---------------------------------------------------------------------------
// K6: out[b][o][y][x] = sum_c48 wp[o][c] * Osp[b][c][y][x]. grid (16,16,8).
// ---------------------------------------------------------------------------
__global__ __launch_bounds__(256) void k_proj(const unsigned short* __restrict__ Od,
                                              const float* __restrict__ wp,
                                              float* __restrict__ out)
{
  __shared__ unsigned short sm6[21888];   // B[256][72]@0 + A[48][72]@18432; reuse lo fp32[16][264]
  unsigned short* const lb = sm6;
  unsigned short* const la = sm6 + 18432;
  float* const lo = (float*)sm6;
  const int t = threadIdx.x;
  const int w = blockIdx.x, h = blockIdx.y, b = blockIdx.z;
  for (int j = t; j < 10944; j += 256) ((unsigned*)sm6)[j] = 0u;
  __syncthreads();
  for (int j = t; j < 2304; j += 256){
    int m = j / 48, k = j - m * 48;
    la[m * 72 + k] = f2bf(wp[j]);
  }
  for (int j = t; j < 768; j += 256){
    int cp = j >> 5, nc = j & 31;
    int ch0 = 2 * cp;
    int head = ch0 / 6, cc = ch0 - head * 6;
    const unsigned short* r0 = Od + (((size_t)(b * 8 + head)) * 1536 + cc * 256 + h * 16 + w) * 256 + nc * 8;
    uint4 q0 = *(const uint4*)r0;
    uint4 q1 = *(const uint4*)(r0 + 65536);  // channel+1 = d+256 -> +65536 shorts
    const unsigned short* u0 = (const unsigned short*)&q0;
    const unsigned short* u1 = (const unsigned short*)&q1;
    unsigned* dst = (unsigned*)lb;
    int cx = (nc & 7) << 2;
    #pragma unroll
    for (int i = 0; i < 8; i++)
      dst[(nc * 8 + i) * 36 + (cp ^ cx)] = (unsigned)u0[i] | ((unsigned)u1[i] << 16);
  }
  __syncthreads();

  const int lane = t & 63, wv = t >> 6;
  const int m15 = lane & 15, quad = lane >> 4;
  const int n0w = wv << 6;
  f32x4 acc[3][4];
  f32x4 z = {0.f,0.f,0.f,0.f};
  #pragma unroll
  for (int i = 0; i < 3; i++)
    #pragma unroll
    for (int j = 0; j < 4; j++) acc[i][j] = z;
  #pragma unroll
  for (int ks = 0; ks < 2; ks++){
    short8 bfr[4];
    #pragma unroll
    for (int nt = 0; nt < 4; nt++){
      int rb = n0w + nt * 16 + m15;
      bfr[nt] = *(const short8*)(lb + rb * 72 + (((4 * ks + quad) ^ ((rb >> 3) & 7)) << 3));
    }
    #pragma unroll
    for (int mt = 0; mt < 3; mt++){
      short8 afr = *(const short8*)(la + (mt * 16 + m15) * 72 + ks * 32 + quad * 8);
      #pragma unroll
      for (int nt = 0; nt < 4; nt++)
        acc[mt][nt] = __builtin_amdgcn_mfma_f32_16x16x32_bf16(afr, bfr[nt], acc[mt][nt], 0, 0, 0);
    }
  }
  for (int mt = 0; mt < 3; mt++){
    __syncthreads();
    #pragma unroll
    for (int nt = 0; nt < 4; nt++)
      #pragma unroll
      for (int r = 0; r < 4; r++){
        int n = n0w + nt * 16 + m15;
        lo[(quad * 4 + r) * 264 + ((n & 0xF0) | ((n & 15) ^ (n >> 4)))] = acc[mt][nt][r];
      }
    __syncthreads();
    int fy = t >> 4, fx = t & 15;
    #pragma unroll
    for (int r = 0; r < 16; r++){
      float v = lo[r * 264 + fx * 16 + (fy ^ fx)];
      out[((size_t)(b * 48 + mt * 16 + r)) * 65536 + (h * 16 + fy) * 256 + w * 16 + fx] = v;
    }
  }
}

// ---------------------------------------------------------------------------
extern "C" void kernel_launch(void* const* d_in, const int* in_sizes, int n_in,
                              void* d_out, int out_size, void* d_ws, size_t ws_size,
                              hipStream_t stream)
{
  (void)in_sizes; (void)n_in; (void)out_size; (void)ws_size;
  const float* x  = (const float*)d_in[0];
  const float* wq = (const float*)d_in[1];
  const float* wd = (const float*)d_in[2];
  const float* wp = (const float*)d_in[3];
  const float* tp = (const float*)d_in[4];
  float* out = (float*)d_out;
  char* ws = (char*)d_ws;

  unsigned short* qkv = (unsigned short*)ws;                 // [0, 151 MB)
  unsigned short* Qd  = (unsigned short*)(ws + 150994944);   // tokens (contiguous Q,K,V)
  unsigned short* Kd  = (unsigned short*)(ws + 201326592);
  unsigned short* Vd  = (unsigned short*)(ws + 251658240);
  float*          S   = (float*)ws;                          // reuses qkv (dead after k_dw)
  unsigned short* P   = (unsigned short*)(ws + 16777216);
  float*          nrm = (float*)(ws + 301989888);            // [2][64][256] f32
  unsigned short* Od  = Qd;                                  // reuses Qd (dead after sgemm)

  k_qkv    <<<4096,              256, 0, stream>>>(x, wq, qkv);
  k_dw     <<<dim3(2, 16, 576),  256, 0, stream>>>(qkv, wd, Qd);
  k_sgemm  <<<dim3(4, 64),       256, 0, stream>>>(Qd, Kd, S, nrm);
  k_softmax<<<dim3(64, 64),      256, 0, stream>>>(S, nrm, tp, P);
  k_ogemm  <<<dim3(24, 64),      256, 0, stream>>>(Vd, P, Od);
  k_proj   <<<dim3(16, 16, 8),   256, 0, stream>>>(Od, wp, out);
}

// Round 6
// 485.012 us; speedup vs baseline: 1.0137x; 1.0137x over previous
//
#include <hip/hip_runtime.h>
#include <stdint.h>

// ---------------------------------------------------------------------------
// Attention_global: B=8,C=48,H=W=256,HEADS=8,FCT=16 -> per (b,head): N=256
// tokens (n=fx*16+fy), d=1536 (d=c*256+h*16+w), c=6.
// R11 (resubmit; previous round died on container acquisition, no GPU data):
// k_dw 512-thread blocks: cl = t>>8 -> ONE uint4 store per thread
// (R8's clean-write property) + 128-wide tile (R10's clean-fetch property).
// Empirical rule from R7-R10 counters: 1 store/thread = WRITE clean (147MB);
// 2 stores/thread from unrolled loop = 1.5x write amplification.
// Norms fused in k_sgemm (R8, proven). ws peak = 302,120,960 B.
// ---------------------------------------------------------------------------

#define DI __device__ __forceinline__
typedef __attribute__((ext_vector_type(8))) short short8;
typedef __attribute__((ext_vector_type(4))) float f32x4;

DI unsigned short f2bf(float f){
  unsigned u = __float_as_uint(f);
  unsigned r = (u + 0x7FFFu + ((u >> 16) & 1u)) >> 16;
  return (unsigned short)r;
}
DI float bf2f(unsigned short h){ return __uint_as_float(((unsigned)h) << 16); }

// ---------------------------------------------------------------------------
// K1a: qkv[b][o][p] = sum_c wq[o][c] * x[b][c][p], o in [0,144).
// MFMA M=144,K=48(pad 64),N=128 px/block. grid 4096.
// ---------------------------------------------------------------------------
__global__ __launch_bounds__(256) void k_qkv(const float* __restrict__ x,
                                             const float* __restrict__ wq,
                                             unsigned short* __restrict__ qkv)
{
  __shared__ unsigned short sm[19584]; // A[144][72]@0 + B[128][72]@10368; reuse D[144][136]
  unsigned short* const lA = sm;
  unsigned short* const lB = sm + 10368;
  const int t = threadIdx.x;
  const int g0 = blockIdx.x << 7;
  const int b  = g0 >> 16;
  const int p0 = g0 & 65535;

  for (int i = t; i < 9792; i += 256) ((unsigned*)sm)[i] = 0u; // k-pad must be 0
  __syncthreads();
  for (int j = t; j < 6912; j += 256){
    int m = j / 48, k = j - m * 48;
    lA[m * 72 + k] = f2bf(wq[j]);
  }
  // B = x^T tile [pixel][k=c]: bf16-pair pack + XOR block swizzle
  for (int j = t; j < 384; j += 256){
    int cp = j >> 4, nc = j & 15;
    const float* xr = x + ((size_t)(b * 48 + 2 * cp)) * 65536 + p0 + nc * 8;
    float4 a0 = *(const float4*)xr;
    float4 a1 = *(const float4*)(xr + 4);
    float4 b0 = *(const float4*)(xr + 65536);
    float4 b1 = *(const float4*)(xr + 65536 + 4);
    float r0[8] = {a0.x,a0.y,a0.z,a0.w,a1.x,a1.y,a1.z,a1.w};
    float r1[8] = {b0.x,b0.y,b0.z,b0.w,b1.x,b1.y,b1.z,b1.w};
    unsigned* dst = (unsigned*)lB;
    int cx = (nc & 7) << 2;
    #pragma unroll
    for (int i = 0; i < 8; i++)
      dst[(nc * 8 + i) * 36 + (cp ^ cx)] =
        (unsigned)f2bf(r0[i]) | ((unsigned)f2bf(r1[i]) << 16);
  }
  __syncthreads();

  const int lane = t & 63, wv = t >> 6;
  const int m15 = lane & 15, quad = lane >> 4;
  const int nw = wv << 5;
  f32x4 acc[9][2];
  f32x4 z = {0.f,0.f,0.f,0.f};
  #pragma unroll
  for (int i = 0; i < 9; i++){ acc[i][0] = z; acc[i][1] = z; }

  #pragma unroll
  for (int ks = 0; ks < 2; ks++){
    short8 bfr[2];
    #pragma unroll
    for (int nt = 0; nt < 2; nt++){
      int row = nw + nt * 16 + m15;
      bfr[nt] = *(const short8*)(lB + row * 72 + (((4 * ks + quad) ^ ((row >> 3) & 7)) << 3));
    }
    #pragma unroll
    for (int mt = 0; mt < 9; mt++){
      short8 afr = *(const short8*)(lA + (mt * 16 + m15) * 72 + ks * 32 + quad * 8);
      acc[mt][0] = __builtin_amdgcn_mfma_f32_16x16x32_bf16(afr, bfr[0], acc[mt][0], 0, 0, 0);
      acc[mt][1] = __builtin_amdgcn_mfma_f32_16x16x32_bf16(afr, bfr[1], acc[mt][1], 0, 0, 0);
    }
  }
  __syncthreads();
  #pragma unroll
  for (int mt = 0; mt < 9; mt++)
    #pragma unroll
    for (int nt = 0; nt < 2; nt++)
      #pragma unroll
      for (int r = 0; r < 4; r++)
        sm[(mt * 16 + quad * 4 + r) * 136 + nw + nt * 16 + m15] = f2bf(acc[mt][nt][r]);
  __syncthreads();
  for (int j = t; j < 2304; j += 256){
    int o = j >> 4, oc = j & 15;
    *(uint4*)(qkv + ((size_t)(b * 144 + o)) * 65536 + p0 + oc * 8) =
      *(const uint4*)(sm + o * 136 + oc * 8);
  }
}

// ---------------------------------------------------------------------------
// K1b: depthwise 3x3 (SAME) over qkv (144 ch); writes Q/K/V tokens bf16.
// grid (2, 16, 8*72): z = b*72+cg, ch0=2cg; block = 512 thr = 2ch x 128 cols
// x 16 rows. LDS column-major [cl][130 cols][32 slots], granule-XOR
// slot = ((gr ^ ((cx>>1)&3))<<3)+rl. Thread = (cl = t>>8, x = (t&255)>>1,
// yg = t&1): 8 consecutive fy -> ONE uint4 store (wave = contiguous 1KB).
// ---------------------------------------------------------------------------
__global__ __launch_bounds__(512) void k_dw(const unsigned short* __restrict__ qkv,
                                            const float* __restrict__ wd,
                                            unsigned short* __restrict__ tok0)
{
  __shared__ unsigned short tile[2][4160];   // 2 x 130 x 32 = 16640B
  const int t = threadIdx.x;
  const int wgx = blockIdx.x, hb = blockIdx.y;
  const int b = blockIdx.z / 72, cg = blockIdx.z % 72;
  const int ch0 = cg * 2;
  const int y0 = hb << 4, xg = wgx << 7;

  // interior staging: 2ch x 18 rows x 16 segs of 8px; rotated scalar writes
  for (int j = t; j < 576; j += 512){
    int rowch = j >> 4, seg = j & 15;
    int cl = rowch >= 18, row = rowch - cl * 18;
    int y = y0 - 1 + row;
    uint4 v = {0u,0u,0u,0u};
    if ((unsigned)y < 256u)
      v = *(const uint4*)(qkv + ((size_t)(b*144 + ch0 + cl))*65536 + y*256 + xg + seg*8);
    const unsigned short* u = (const unsigned short*)&v;
    int gr = row >> 3, rl = row & 7;
    #pragma unroll
    for (int i = 0; i < 8; i++){
      int ii = (i + seg) & 7;
      int cx = seg * 8 + ii + 1;
      tile[cl][cx * 32 + ((gr ^ ((cx >> 1) & 3)) << 3) + rl] = u[ii];
    }
  }
  // halo cols: global x = xg-1 -> cx 0, x = xg+128 -> cx 129
  if (t < 72){
    int rowch = t >> 1, side = t & 1;
    int cl = rowch >= 18, row = rowch - cl * 18;
    int y = y0 - 1 + row;
    int xx = side ? (xg + 128) : (xg - 1);
    unsigned short v = 0;
    if ((unsigned)y < 256u && (unsigned)xx < 256u)
      v = qkv[((size_t)(b*144 + ch0 + cl))*65536 + y*256 + xx];
    int cx = side ? 129 : 0;
    tile[cl][cx * 32 + (((row >> 3) ^ ((cx >> 1) & 3)) << 3) + (row & 7)] = v;
  }
  __syncthreads();

  const int cl = t >> 8, q = t & 255;
  const int x = q >> 1, yg = q & 1;
  const int ch = ch0 + cl;
  float w9[9];
  #pragma unroll
  for (int i = 0; i < 9; i++) w9[i] = wd[ch * 9 + i];   // wave-uniform (t>>8 const/wave)
  float o[8] = {0.f,0.f,0.f,0.f,0.f,0.f,0.f,0.f};
  #pragma unroll
  for (int dx = 0; dx < 3; dx++){
    int cx = x + dx;                         // global cols x-1 .. x+1
    const unsigned short* cb = tile[cl] + cx * 32;
    int sw = (cx >> 1) & 3;
    uint4 va = *(const uint4*)(cb + ((yg ^ sw) << 3));              // rows yg*8+0..7
    unsigned vc = *(const unsigned*)(cb + (((yg + 1) ^ sw) << 3));  // rows yg*8+8,9
    float fv[10];
    fv[0] = __uint_as_float(va.x << 16);
    fv[1] = __uint_as_float(va.x & 0xffff0000u);
    fv[2] = __uint_as_float(va.y << 16);
    fv[3] = __uint_as_float(va.y & 0xffff0000u);
    fv[4] = __uint_as_float(va.z << 16);
    fv[5] = __uint_as_float(va.z & 0xffff0000u);
    fv[6] = __uint_as_float(va.w << 16);
    fv[7] = __uint_as_float(va.w & 0xffff0000u);
    fv[8] = __uint_as_float(vc << 16);
    fv[9] = __uint_as_float(vc & 0xffff0000u);
    #pragma unroll
    for (int r = 0; r < 8; r++)
      o[r] = fmaf(fv[r],     w9[dx],
             fmaf(fv[r + 1], w9[3 + dx],
             fmaf(fv[r + 2], w9[6 + dx], o[r])));
  }
  // one contiguous 16B store: n = fx*16 + yg*8 + (0..7)
  const int split = ch / 48;
  const int chs = ch - split * 48;
  const int head = chs / 6, ccb = chs - head * 6;
  const int fx = x & 15, wp = wgx * 8 + (x >> 4);
  uint4 pk;
  asm("v_cvt_pk_bf16_f32 %0, %1, %2" : "=v"(pk.x) : "v"(o[0]), "v"(o[1]));
  asm("v_cvt_pk_bf16_f32 %0, %1, %2" : "=v"(pk.y) : "v"(o[2]), "v"(o[3]));
  asm("v_cvt_pk_bf16_f32 %0, %1, %2" : "=v"(pk.z) : "v"(o[4]), "v"(o[5]));
  asm("v_cvt_pk_bf16_f32 %0, %1, %2" : "=v"(pk.w) : "v"(o[6]), "v"(o[7]));
  *(uint4*)(tok0 + (size_t)split * 25165824
            + ((size_t)(b * 8 + head)) * 393216
            + ((size_t)(ccb * 256 + hb * 16 + wp)) * 256 + fx * 16 + yg * 8) = pk;
}

// ---------------------------------------------------------------------------
// K3: S[bh][n][m] = sum_d Q[bh][d][n]*K[bh][d][m]. 128x128/block, grid (4,64).
// Fused l2-norm sums (R8, proven): m0==0 blocks sum Q^2 per n, n0==0 blocks
// sum K^2 per m; shfl+LDS reduce, direct write (no atomics).
// ---------------------------------------------------------------------------
__global__ __launch_bounds__(256) void k_sgemm(const unsigned short* __restrict__ Qd,
                                               const unsigned short* __restrict__ Kd,
                                               float* __restrict__ S,
                                               float* __restrict__ nrm)
{
  __shared__ unsigned short sm[18432];
  unsigned short* const sa = sm;
  unsigned short* const sb = sm + 9216;
  const int t = threadIdx.x;
  const int bh = blockIdx.y;
  const int n0 = (blockIdx.x >> 1) << 7;
  const int m0 = (blockIdx.x & 1) << 7;
  const int lane = t & 63, wv = t >> 6;
  const int m15 = lane & 15, quad = lane >> 4;
  const int wm = (wv & 1) << 6, wn = (wv >> 1) << 6;
  const size_t base = (size_t)bh * 393216;
  f32x4 acc[4][4];
  f32x4 z = {0.f,0.f,0.f,0.f};
  #pragma unroll
  for (int i = 0; i < 4; i++)
    #pragma unroll
    for (int j = 0; j < 4; j++) acc[i][j] = z;
  float aq[8] = {0.f,0.f,0.f,0.f,0.f,0.f,0.f,0.f};
  float ak[8] = {0.f,0.f,0.f,0.f,0.f,0.f,0.f,0.f};

  const int kpb = t >> 4, nc = t & 15;
  const int cxs = (nc & 7) << 2;
  for (int s = 0; s < 24; s++){
    __syncthreads();
    #pragma unroll
    for (int kk = 0; kk < 2; kk++){
      int kp = kpb + kk * 16;
      const unsigned short* srcq = Qd + base + (size_t)(s * 64 + 2 * kp) * 256 + n0 + nc * 8;
      uint4 q0 = *(const uint4*)srcq;
      uint4 q1 = *(const uint4*)(srcq + 256);
      const unsigned short* u0 = (const unsigned short*)&q0;
      const unsigned short* u1 = (const unsigned short*)&q1;
      unsigned* dsta = (unsigned*)sa;
      #pragma unroll
      for (int i = 0; i < 8; i++){
        dsta[(nc * 8 + i) * 36 + (kp ^ cxs)] = (unsigned)u0[i] | ((unsigned)u1[i] << 16);
        if (m0 == 0){
          float f0 = bf2f(u0[i]), f1 = bf2f(u1[i]);
          aq[i] = fmaf(f0, f0, fmaf(f1, f1, aq[i]));
        }
      }
      const unsigned short* srck = Kd + base + (size_t)(s * 64 + 2 * kp) * 256 + m0 + nc * 8;
      uint4 k0 = *(const uint4*)srck;
      uint4 k1 = *(const uint4*)(srck + 256);
      const unsigned short* v0 = (const unsigned short*)&k0;
      const unsigned short* v1 = (const unsigned short*)&k1;
      unsigned* dstb = (unsigned*)sb;
      #pragma unroll
      for (int i = 0; i < 8; i++){
        dstb[(nc * 8 + i) * 36 + (kp ^ cxs)] = (unsigned)v0[i] | ((unsigned)v1[i] << 16);
        if (n0 == 0){
          float f0 = bf2f(v0[i]), f1 = bf2f(v1[i]);
          ak[i] = fmaf(f0, f0, fmaf(f1, f1, ak[i]));
        }
      }
    }
    __syncthreads();
    #pragma unroll
    for (int ks = 0; ks < 2; ks++){
      short8 afr[4], bfr[4];
      #pragma unroll
      for (int i = 0; i < 4; i++){
        int ra = wm + i * 16 + m15;
        int rb = wn + i * 16 + m15;
        afr[i] = *(const short8*)(sa + ra * 72 + (((4 * ks + quad) ^ ((ra >> 3) & 7)) << 3));
        bfr[i] = *(const short8*)(sb + rb * 72 + (((4 * ks + quad) ^ ((rb >> 3) & 7)) << 3));
      }
      #pragma unroll
      for (int mi = 0; mi < 4; mi++)
        #pragma unroll
        for (int ni = 0; ni < 4; ni++)
          acc[mi][ni] = __builtin_amdgcn_mfma_f32_16x16x32_bf16(afr[mi], bfr[ni], acc[mi][ni], 0, 0, 0);
    }
  }

  // fused norm reduce: in-wave over kp (^16,^32), cross-wave via LDS
  __syncthreads();
  float* nb = (float*)sm;                 // 1024 floats (within sa region)
  #pragma unroll
  for (int i = 0; i < 8; i++){
    aq[i] += __shfl_xor(aq[i], 16); aq[i] += __shfl_xor(aq[i], 32);
    ak[i] += __shfl_xor(ak[i], 16); ak[i] += __shfl_xor(ak[i], 32);
  }
  if (lane < 16){
    #pragma unroll
    for (int i = 0; i < 8; i++){
      nb[wv * 128 + m15 * 8 + i]       = aq[i];
      nb[512 + wv * 128 + m15 * 8 + i] = ak[i];
    }
  }
  __syncthreads();
  if (m0 == 0 && t < 128)
    nrm[(size_t)bh * 256 + n0 + t] = nb[t] + nb[128 + t] + nb[256 + t] + nb[384 + t];
  if (n0 == 0 && t >= 128){
    int m = t - 128;
    nrm[16384 + (size_t)bh * 256 + m0 + m] =
      nb[512 + m] + nb[640 + m] + nb[768 + m] + nb[896 + m];
  }

  #pragma unroll
  for (int mi = 0; mi < 4; mi++)
    #pragma unroll
    for (int ni = 0; ni < 4; ni++)
      #pragma unroll
      for (int r = 0; r < 4; r++){
        int nr = n0 + wm + mi * 16 + quad * 4 + r;
        int mc = m0 + wn + ni * 16 + m15;
        S[(size_t)bh * 65536 + (size_t)nr * 256 + mc] = acc[mi][ni][r];
      }
}

// ---------------------------------------------------------------------------
// K4: softmax_1 with l2-norm scaling + temperature (reads fused norms).
// ---------------------------------------------------------------------------
__global__ __launch_bounds__(256) void k_softmax(const float* __restrict__ S,
                                                 const float* __restrict__ nrm,
                                                 const float* __restrict__ temp,
                                                 unsigned short* __restrict__ P)
{
  const int t = threadIdx.x, lane = t & 63, wv = t >> 6;
  const int bh = blockIdx.y;
  const int n = blockIdx.x * 4 + wv;
  const float tp = temp[bh & 7];
  const size_t ro = (size_t)bh * 65536 + (size_t)n * 256;
  float4 sv = *(const float4*)(S + ro + lane * 4);
  float4 ka = *(const float4*)(nrm + 16384 + (size_t)bh * 256 + lane * 4);
  float nqv = nrm[(size_t)bh * 256 + n];
  float qi = tp / fmaxf(sqrtf(fmaxf(nqv, 0.f)), 1e-12f);
  float i0 = 1.f / fmaxf(sqrtf(fmaxf(ka.x, 0.f)), 1e-12f);
  float i1 = 1.f / fmaxf(sqrtf(fmaxf(ka.y, 0.f)), 1e-12f);
  float i2 = 1.f / fmaxf(sqrtf(fmaxf(ka.z, 0.f)), 1e-12f);
  float i3 = 1.f / fmaxf(sqrtf(fmaxf(ka.w, 0.f)), 1e-12f);
  float e0 = __expf(fminf(sv.x * qi * i0, 60.f));
  float e1 = __expf(fminf(sv.y * qi * i1, 60.f));
  float e2 = __expf(fminf(sv.z * qi * i2, 60.f));
  float e3 = __expf(fminf(sv.w * qi * i3, 60.f));
  float ss = e0 + e1 + e2 + e3;
  #pragma unroll
  for (int o = 32; o > 0; o >>= 1) ss += __shfl_xor(ss, o);
  float inv = 1.f / (ss + 1.f);
  uint2 pv;
  pv.x = (unsigned)f2bf(e0 * inv) | ((unsigned)f2bf(e1 * inv) << 16);
  pv.y = (unsigned)f2bf(e2 * inv) | ((unsigned)f2bf(e3 * inv) << 16);
  *(uint2*)(P + ro + lane * 4) = pv;
}

// ---------------------------------------------------------------------------
// K5: O[bh][d][n] = sum_m V[bh][d][m] * P[bh][n][m]. 128x128/block, grid(24,64).
// ---------------------------------------------------------------------------
__global__ __launch_bounds__(256) void k_ogemm(const unsigned short* __restrict__ Vd,
                                               const unsigned short* __restrict__ P,
                                               unsigned short* __restrict__ Od)
{
  __shared__ unsigned short sm[18432];
  unsigned short* const sa = sm;
  unsigned short* const sb = sm + 9216;
  const int t = threadIdx.x;
  const int bh = blockIdx.y;
  const int d0 = (blockIdx.x >> 1) << 7;
  const int n0 = (blockIdx.x & 1) << 7;
  const int lane = t & 63, wv = t >> 6;
  const int m15 = lane & 15, quad = lane >> 4;
  const int wm = (wv & 1) << 6, wn = (wv >> 1) << 6;
  f32x4 acc[4][4];
  f32x4 z = {0.f,0.f,0.f,0.f};
  #pragma unroll
  for (int i = 0; i < 4; i++)
    #pragma unroll
    for (int j = 0; j < 4; j++) acc[i][j] = z;

  for (int s = 0; s < 4; s++){
    __syncthreads();
    for (int j = t; j < 512; j += 256){
      int hf = j >> 8, jj = j & 255;
      int row = jj >> 1, hh = jj & 1;
      const unsigned short* src = hf
        ? (P  + (size_t)bh * 65536  + (size_t)(n0 + row) * 256 + s * 64 + hh * 32)
        : (Vd + (size_t)bh * 393216 + (size_t)(d0 + row) * 256 + s * 64 + hh * 32);
      uint4 v0 = *(const uint4*)src;
      uint4 v1 = *(const uint4*)(src + 8);
      uint4 v2 = *(const uint4*)(src + 16);
      uint4 v3 = *(const uint4*)(src + 24);
      unsigned* dst = (unsigned*)(hf ? sb : sa) + row * 36 + hh * 16;
      *(uint4*)dst        = v0;
      *(uint4*)(dst + 4)  = v1;
      *(uint4*)(dst + 8)  = v2;
      *(uint4*)(dst + 12) = v3;
    }
    __syncthreads();
    #pragma unroll
    for (int ks = 0; ks < 2; ks++){
      short8 afr[4], bfr[4];
      #pragma unroll
      for (int i = 0; i < 4; i++){
        afr[i] = *(const short8*)(sa + (wm + i * 16 + m15) * 72 + ks * 32 + quad * 8);
        bfr[i] = *(const short8*)(sb + (wn + i * 16 + m15) * 72 + ks * 32 + quad * 8);
      }
      #pragma unroll
      for (int mi = 0; mi < 4; mi++)
        #pragma unroll
        for (int ni = 0; ni < 4; ni++)
          acc[mi][ni] = __builtin_amdgcn_mfma_f32_16x16x32_bf16(afr[mi], bfr[ni], acc[mi][ni], 0, 0, 0);
    }
  }
  __syncthreads();
  #pragma unroll
  for (int mi = 0; mi < 4; mi++)
    #pragma unroll
    for (int ni = 0; ni < 4; ni++)
      #pragma unroll
      for (int r = 0; r < 4; r++)
        sm[(wm + mi * 16 + quad * 4 + r) * 136 + wn + ni * 16 + m15] = f2bf(acc[mi][ni][r]);
  __syncthreads();
  {
    int row = t >> 1, hh = t & 1;
    const unsigned short* lp = sm + row * 136 + hh * 64;
    unsigned short* gp = Od + (size_t)bh * 393216 + (size_t)(d0 + row) * 256 + n0 + hh * 64;
    #pragma unroll
    for (int u = 0; u < 8; u++)
      *(uint4*)(gp + u * 8) = *(const uint4*)(lp + u * 8);
  }
}

// ---------------------------------------------------------------------------
// K6: out[b][o][y][x] = sum_c48 wp[o][c] * Osp[b][c][y][x]. grid (16,16,8).
// ---------------------------------------------------------------------------
__global__ __launch_bounds__(256) void k_proj(const unsigned short* __restrict__ Od,
                                              const float* __restrict__ wp,
                                              float* __restrict__ out)
{
  __shared__ unsigned short sm6[21888];   // B[256][72]@0 + A[48][72]@18432; reuse lo fp32[16][264]
  unsigned short* const lb = sm6;
  unsigned short* const la = sm6 + 18432;
  float* const lo = (float*)sm6;
  const int t = threadIdx.x;
  const int w = blockIdx.x, h = blockIdx.y, b = blockIdx.z;
  for (int j = t; j < 10944; j += 256) ((unsigned*)sm6)[j] = 0u;
  __syncthreads();
  for (int j = t; j < 2304; j += 256){
    int m = j / 48, k = j - m * 48;
    la[m * 72 + k] = f2bf(wp[j]);
  }
  for (int j = t; j < 768; j += 256){
    int cp = j >> 5, nc = j & 31;
    int ch0 = 2 * cp;
    int head = ch0 / 6, cc = ch0 - head * 6;
    const unsigned short* r0 = Od + (((size_t)(b * 8 + head)) * 1536 + cc * 256 + h * 16 + w) * 256 + nc * 8;
    uint4 q0 = *(const uint4*)r0;
    uint4 q1 = *(const uint4*)(r0 + 65536);  // channel+1 = d+256 -> +65536 shorts
    const unsigned short* u0 = (const unsigned short*)&q0;
    const unsigned short* u1 = (const unsigned short*)&q1;
    unsigned* dst = (unsigned*)lb;
    int cx = (nc & 7) << 2;
    #pragma unroll
    for (int i = 0; i < 8; i++)
      dst[(nc * 8 + i) * 36 + (cp ^ cx)] = (unsigned)u0[i] | ((unsigned)u1[i] << 16);
  }
  __syncthreads();

  const int lane = t & 63, wv = t >> 6;
  const int m15 = lane & 15, quad = lane >> 4;
  const int n0w = wv << 6;
  f32x4 acc[3][4];
  f32x4 z = {0.f,0.f,0.f,0.f};
  #pragma unroll
  for (int i = 0; i < 3; i++)
    #pragma unroll
    for (int j = 0; j < 4; j++) acc[i][j] = z;
  #pragma unroll
  for (int ks = 0; ks < 2; ks++){
    short8 bfr[4];
    #pragma unroll
    for (int nt = 0; nt < 4; nt++){
      int rb = n0w + nt * 16 + m15;
      bfr[nt] = *(const short8*)(lb + rb * 72 + (((4 * ks + quad) ^ ((rb >> 3) & 7)) << 3));
    }
    #pragma unroll
    for (int mt = 0; mt < 3; mt++){
      short8 afr = *(const short8*)(la + (mt * 16 + m15) * 72 + ks * 32 + quad * 8);
      #pragma unroll
      for (int nt = 0; nt < 4; nt++)
        acc[mt][nt] = __builtin_amdgcn_mfma_f32_16x16x32_bf16(afr, bfr[nt], acc[mt][nt], 0, 0, 0);
    }
  }
  for (int mt = 0; mt < 3; mt++){
    __syncthreads();
    #pragma unroll
    for (int nt = 0; nt < 4; nt++)
      #pragma unroll
      for (int r = 0; r < 4; r++){
        int n = n0w + nt * 16 + m15;
        lo[(quad * 4 + r) * 264 + ((n & 0xF0) | ((n & 15) ^ (n >> 4)))] = acc[mt][nt][r];
      }
    __syncthreads();
    int fy = t >> 4, fx = t & 15;
    #pragma unroll
    for (int r = 0; r < 16; r++){
      float v = lo[r * 264 + fx * 16 + (fy ^ fx)];
      out[((size_t)(b * 48 + mt * 16 + r)) * 65536 + (h * 16 + fy) * 256 + w * 16 + fx] = v;
    }
  }
}

// ---------------------------------------------------------------------------
extern "C" void kernel_launch(void* const* d_in, const int* in_sizes, int n_in,
                              void* d_out, int out_size, void* d_ws, size_t ws_size,
                              hipStream_t stream)
{
  (void)in_sizes; (void)n_in; (void)out_size; (void)ws_size;
  const float* x  = (const float*)d_in[0];
  const float* wq = (const float*)d_in[1];
  const float* wd = (const float*)d_in[2];
  const float* wp = (const float*)d_in[3];
  const float* tp = (const float*)d_in[4];
  float* out = (float*)d_out;
  char* ws = (char*)d_ws;

  unsigned short* qkv = (unsigned short*)ws;                 // [0, 151 MB)
  unsigned short* Qd  = (unsigned short*)(ws + 150994944);   // tokens (contiguous Q,K,V)
  unsigned short* Kd  = (unsigned short*)(ws + 201326592);
  unsigned short* Vd  = (unsigned short*)(ws + 251658240);
  float*          S   = (float*)ws;                          // reuses qkv (dead after k_dw)
  unsigned short* P   = (unsigned short*)(ws + 16777216);
  float*          nrm = (float*)(ws + 301989888);            // [2][64][256] f32
  unsigned short* Od  = Qd;                                  // reuses Qd (dead after sgemm)

  k_qkv    <<<4096,              256, 0, stream>>>(x, wq, qkv);
  k_dw     <<<dim3(2, 16, 576),  512, 0, stream>>>(qkv, wd, Qd);
  k_sgemm  <<<dim3(4, 64),       256, 0, stream>>>(Qd, Kd, S, nrm);
  k_softmax<<<dim3(64, 64),      256, 0, stream>>>(S, nrm, tp, P);
  k_ogemm  <<<dim3(24, 64),      256, 0, stream>>>(Vd, P, Od);
  k_proj   <<<dim3(16, 16, 8),   256, 0, stream>>>(Od, wp, out);
}

// Round 8
// 446.155 us; speedup vs baseline: 1.1020x; 1.0871x over previous
//
#include <hip/hip_runtime.h>
#include <stdint.h>

// ---------------------------------------------------------------------------
// Attention_global: B=8,C=48,H=W=256,HEADS=8,FCT=16 -> per (b,head): N=256
// tokens (n=fx*16+fy), d=1536 (d=c*256+h*16+w), c=6.
// R12 (resubmit; previous round died on container acquisition, no GPU data):
// k_dw row-major LDS tile [cl][18][148] (stride 296B == 8 mod 16):
// staging = 2x aligned ds_write_b64 per uint4 (no rotation/scalar scatter);
// compute = 30x ds_read_u16 from ONE base vgpr + immediate offsets
// (r*296+dx*2). Bank math: yg contributes 8*74 == 16 mod 32 -> yg halves
// use disjoint bank halves -> 2 lanes/bank = free. Store path = R11 (one
// uint4/thread, WRITE clean 147MB proven). Norms fused in k_sgemm (R8).
// ws peak = 302,120,960 B.
// ---------------------------------------------------------------------------

#define DI __device__ __forceinline__
typedef __attribute__((ext_vector_type(8))) short short8;
typedef __attribute__((ext_vector_type(4))) float f32x4;

DI unsigned short f2bf(float f){
  unsigned u = __float_as_uint(f);
  unsigned r = (u + 0x7FFFu + ((u >> 16) & 1u)) >> 16;
  return (unsigned short)r;
}
DI float bf2f(unsigned short h){ return __uint_as_float(((unsigned)h) << 16); }

// ---------------------------------------------------------------------------
// K1a: qkv[b][o][p] = sum_c wq[o][c] * x[b][c][p], o in [0,144).
// MFMA M=144,K=48(pad 64),N=128 px/block. grid 4096.
// ---------------------------------------------------------------------------
__global__ __launch_bounds__(256) void k_qkv(const float* __restrict__ x,
                                             const float* __restrict__ wq,
                                             unsigned short* __restrict__ qkv)
{
  __shared__ unsigned short sm[19584]; // A[144][72]@0 + B[128][72]@10368; reuse D[144][136]
  unsigned short* const lA = sm;
  unsigned short* const lB = sm + 10368;
  const int t = threadIdx.x;
  const int g0 = blockIdx.x << 7;
  const int b  = g0 >> 16;
  const int p0 = g0 & 65535;

  for (int i = t; i < 9792; i += 256) ((unsigned*)sm)[i] = 0u; // k-pad must be 0
  __syncthreads();
  for (int j = t; j < 6912; j += 256){
    int m = j / 48, k = j - m * 48;
    lA[m * 72 + k] = f2bf(wq[j]);
  }
  // B = x^T tile [pixel][k=c]: bf16-pair pack + XOR block swizzle
  for (int j = t; j < 384; j += 256){
    int cp = j >> 4, nc = j & 15;
    const float* xr = x + ((size_t)(b * 48 + 2 * cp)) * 65536 + p0 + nc * 8;
    float4 a0 = *(const float4*)xr;
    float4 a1 = *(const float4*)(xr + 4);
    float4 b0 = *(const float4*)(xr + 65536);
    float4 b1 = *(const float4*)(xr + 65536 + 4);
    float r0[8] = {a0.x,a0.y,a0.z,a0.w,a1.x,a1.y,a1.z,a1.w};
    float r1[8] = {b0.x,b0.y,b0.z,b0.w,b1.x,b1.y,b1.z,b1.w};
    unsigned* dst = (unsigned*)lB;
    int cx = (nc & 7) << 2;
    #pragma unroll
    for (int i = 0; i < 8; i++)
      dst[(nc * 8 + i) * 36 + (cp ^ cx)] =
        (unsigned)f2bf(r0[i]) | ((unsigned)f2bf(r1[i]) << 16);
  }
  __syncthreads();

  const int lane = t & 63, wv = t >> 6;
  const int m15 = lane & 15, quad = lane >> 4;
  const int nw = wv << 5;
  f32x4 acc[9][2];
  f32x4 z = {0.f,0.f,0.f,0.f};
  #pragma unroll
  for (int i = 0; i < 9; i++){ acc[i][0] = z; acc[i][1] = z; }

  #pragma unroll
  for (int ks = 0; ks < 2; ks++){
    short8 bfr[2];
    #pragma unroll
    for (int nt = 0; nt < 2; nt++){
      int row = nw + nt * 16 + m15;
      bfr[nt] = *(const short8*)(lB + row * 72 + (((4 * ks + quad) ^ ((row >> 3) & 7)) << 3));
    }
    #pragma unroll
    for (int mt = 0; mt < 9; mt++){
      short8 afr = *(const short8*)(lA + (mt * 16 + m15) * 72 + ks * 32 + quad * 8);
      acc[mt][0] = __builtin_amdgcn_mfma_f32_16x16x32_bf16(afr, bfr[0], acc[mt][0], 0, 0, 0);
      acc[mt][1] = __builtin_amdgcn_mfma_f32_16x16x32_bf16(afr, bfr[1], acc[mt][1], 0, 0, 0);
    }
  }
  __syncthreads();
  #pragma unroll
  for (int mt = 0; mt < 9; mt++)
    #pragma unroll
    for (int nt = 0; nt < 2; nt++)
      #pragma unroll
      for (int r = 0; r < 4; r++)
        sm[(mt * 16 + quad * 4 + r) * 136 + nw + nt * 16 + m15] = f2bf(acc[mt][nt][r]);
  __syncthreads();
  for (int j = t; j < 2304; j += 256){
    int o = j >> 4, oc = j & 15;
    *(uint4*)(qkv + ((size_t)(b * 144 + o)) * 65536 + p0 + oc * 8) =
      *(const uint4*)(sm + o * 136 + oc * 8);
  }
}

// ---------------------------------------------------------------------------
// K1b: depthwise 3x3 (SAME) over qkv (144 ch); writes Q/K/V tokens bf16.
// grid (2, 16, 8*72); block 512 = 2ch x 128 cols x 2 yg.
// LDS row-major tile[cl][18 rows][148] u16 (stride 296B): col layout
// slot 7 = halo x-1, slots 8..135 = interior, slot 136 = halo x+128.
// Staging: 2x ds_write_b64 per uint4 (aligned, no scatter).
// Compute: thread (cl=t>>8, x=(t&255)>>1, yg=t&1) reads 30 u16 via one base
// + imm offsets (bank-free: yg half-offset 16), 72 scalar fma, one uint4
// store of 8 consecutive fy (wave store = contiguous 1KB, proven clean).
// ---------------------------------------------------------------------------
__global__ __launch_bounds__(512) void k_dw(const unsigned short* __restrict__ qkv,
                                            const float* __restrict__ wd,
                                            unsigned short* __restrict__ tok0)
{
  __shared__ unsigned short tile[2][18][148];   // 10656 B
  const int t = threadIdx.x;
  const int wgx = blockIdx.x, hb = blockIdx.y;
  const int b = blockIdx.z / 72, cg = blockIdx.z % 72;
  const int ch0 = cg * 2;
  const int y0 = hb << 4, xg = wgx << 7;

  // interior staging: 2ch x 18 rows x 16 segs of 8px; two aligned b64 writes
  for (int j = t; j < 576; j += 512){
    int rowch = j >> 4, seg = j & 15;
    int cl = rowch >= 18, row = rowch - cl * 18;
    int y = y0 - 1 + row;
    uint4 v = {0u,0u,0u,0u};
    if ((unsigned)y < 256u)
      v = *(const uint4*)(qkv + ((size_t)(b*144 + ch0 + cl))*65536 + y*256 + xg + seg*8);
    unsigned short* rp = &tile[cl][row][8 + seg * 8];
    uint2 lo; lo.x = v.x; lo.y = v.y;
    uint2 hi; hi.x = v.z; hi.y = v.w;
    *(uint2*)rp       = lo;   // byte off = row*296 + 16 + seg*16 : 8B aligned
    *(uint2*)(rp + 4) = hi;
  }
  // halo cols: global x = xg-1 -> slot 7, x = xg+128 -> slot 136
  if (t < 72){
    int rowch = t >> 1, side = t & 1;
    int cl = rowch >= 18, row = rowch - cl * 18;
    int y = y0 - 1 + row;
    int xx = side ? (xg + 128) : (xg - 1);
    unsigned short v = 0;
    if ((unsigned)y < 256u && (unsigned)xx < 256u)
      v = qkv[((size_t)(b*144 + ch0 + cl))*65536 + y*256 + xx];
    tile[cl][row][side ? 136 : 7] = v;
  }
  __syncthreads();

  const int cl = t >> 8, q = t & 255;
  const int x = q >> 1, yg = q & 1;
  const int ch = ch0 + cl;
  float w9[9];
  #pragma unroll
  for (int i = 0; i < 9; i++) w9[i] = wd[ch * 9 + i];   // wave-uniform (t>>8 const/wave)
  // one base pointer; all 30 reads use compile-time offsets r*296 + dx*2
  const unsigned short* bp = &tile[cl][yg * 8][7 + x];
  float o[8] = {0.f,0.f,0.f,0.f,0.f,0.f,0.f,0.f};
  #pragma unroll
  for (int dx = 0; dx < 3; dx++){
    float fv[10];
    #pragma unroll
    for (int r = 0; r < 10; r++)
      fv[r] = bf2f(bp[r * 148 + dx]);
    #pragma unroll
    for (int r = 0; r < 8; r++)
      o[r] = fmaf(fv[r],     w9[dx],
             fmaf(fv[r + 1], w9[3 + dx],
             fmaf(fv[r + 2], w9[6 + dx], o[r])));
  }
  // one contiguous 16B store: n = fx*16 + yg*8 + (0..7)
  const int split = ch / 48;
  const int chs = ch - split * 48;
  const int head = chs / 6, ccb = chs - head * 6;
  const int fx = x & 15, wp = wgx * 8 + (x >> 4);
  uint4 pk;
  asm("v_cvt_pk_bf16_f32 %0, %1, %2" : "=v"(pk.x) : "v"(o[0]), "v"(o[1]));
  asm("v_cvt_pk_bf16_f32 %0, %1, %2" : "=v"(pk.y) : "v"(o[2]), "v"(o[3]));
  asm("v_cvt_pk_bf16_f32 %0, %1, %2" : "=v"(pk.z) : "v"(o[4]), "v"(o[5]));
  asm("v_cvt_pk_bf16_f32 %0, %1, %2" : "=v"(pk.w) : "v"(o[6]), "v"(o[7]));
  *(uint4*)(tok0 + (size_t)split * 25165824
            + ((size_t)(b * 8 + head)) * 393216
            + ((size_t)(ccb * 256 + hb * 16 + wp)) * 256 + fx * 16 + yg * 8) = pk;
}

// ---------------------------------------------------------------------------
// K3: S[bh][n][m] = sum_d Q[bh][d][n]*K[bh][d][m]. 128x128/block, grid (4,64).
// Fused l2-norm sums (R8, proven): m0==0 blocks sum Q^2 per n, n0==0 blocks
// sum K^2 per m; shfl+LDS reduce, direct write (no atomics).
// ---------------------------------------------------------------------------
__global__ __launch_bounds__(256) void k_sgemm(const unsigned short* __restrict__ Qd,
                                               const unsigned short* __restrict__ Kd,
                                               float* __restrict__ S,
                                               float* __restrict__ nrm)
{
  __shared__ unsigned short sm[18432];
  unsigned short* const sa = sm;
  unsigned short* const sb = sm + 9216;
  const int t = threadIdx.x;
  const int bh = blockIdx.y;
  const int n0 = (blockIdx.x >> 1) << 7;
  const int m0 = (blockIdx.x & 1) << 7;
  const int lane = t & 63, wv = t >> 6;
  const int m15 = lane & 15, quad = lane >> 4;
  const int wm = (wv & 1) << 6, wn = (wv >> 1) << 6;
  const size_t base = (size_t)bh * 393216;
  f32x4 acc[4][4];
  f32x4 z = {0.f,0.f,0.f,0.f};
  #pragma unroll
  for (int i = 0; i < 4; i++)
    #pragma unroll
    for (int j = 0; j < 4; j++) acc[i][j] = z;
  float aq[8] = {0.f,0.f,0.f,0.f,0.f,0.f,0.f,0.f};
  float ak[8] = {0.f,0.f,0.f,0.f,0.f,0.f,0.f,0.f};

  const int kpb = t >> 4, nc = t & 15;
  const int cxs = (nc & 7) << 2;
  for (int s = 0; s < 24; s++){
    __syncthreads();
    #pragma unroll
    for (int kk = 0; kk < 2; kk++){
      int kp = kpb + kk * 16;
      const unsigned short* srcq = Qd + base + (size_t)(s * 64 + 2 * kp) * 256 + n0 + nc * 8;
      uint4 q0 = *(const uint4*)srcq;
      uint4 q1 = *(const uint4*)(srcq + 256);
      const unsigned short* u0 = (const unsigned short*)&q0;
      const unsigned short* u1 = (const unsigned short*)&q1;
      unsigned* dsta = (unsigned*)sa;
      #pragma unroll
      for (int i = 0; i < 8; i++){
        dsta[(nc * 8 + i) * 36 + (kp ^ cxs)] = (unsigned)u0[i] | ((unsigned)u1[i] << 16);
        if (m0 == 0){
          float f0 = bf2f(u0[i]), f1 = bf2f(u1[i]);
          aq[i] = fmaf(f0, f0, fmaf(f1, f1, aq[i]));
        }
      }
      const unsigned short* srck = Kd + base + (size_t)(s * 64 + 2 * kp) * 256 + m0 + nc * 8;
      uint4 k0 = *(const uint4*)srck;
      uint4 k1 = *(const uint4*)(srck + 256);
      const unsigned short* v0 = (const unsigned short*)&k0;
      const unsigned short* v1 = (const unsigned short*)&k1;
      unsigned* dstb = (unsigned*)sb;
      #pragma unroll
      for (int i = 0; i < 8; i++){
        dstb[(nc * 8 + i) * 36 + (kp ^ cxs)] = (unsigned)v0[i] | ((unsigned)v1[i] << 16);
        if (n0 == 0){
          float f0 = bf2f(v0[i]), f1 = bf2f(v1[i]);
          ak[i] = fmaf(f0, f0, fmaf(f1, f1, ak[i]));
        }
      }
    }
    __syncthreads();
    #pragma unroll
    for (int ks = 0; ks < 2; ks++){
      short8 afr[4], bfr[4];
      #pragma unroll
      for (int i = 0; i < 4; i++){
        int ra = wm + i * 16 + m15;
        int rb = wn + i * 16 + m15;
        afr[i] = *(const short8*)(sa + ra * 72 + (((4 * ks + quad) ^ ((ra >> 3) & 7)) << 3));
        bfr[i] = *(const short8*)(sb + rb * 72 + (((4 * ks + quad) ^ ((rb >> 3) & 7)) << 3));
      }
      #pragma unroll
      for (int mi = 0; mi < 4; mi++)
        #pragma unroll
        for (int ni = 0; ni < 4; ni++)
          acc[mi][ni] = __builtin_amdgcn_mfma_f32_16x16x32_bf16(afr[mi], bfr[ni], acc[mi][ni], 0, 0, 0);
    }
  }

  // fused norm reduce: in-wave over kp (^16,^32), cross-wave via LDS
  __syncthreads();
  float* nb = (float*)sm;                 // 1024 floats (within sa region)
  #pragma unroll
  for (int i = 0; i < 8; i++){
    aq[i] += __shfl_xor(aq[i], 16); aq[i] += __shfl_xor(aq[i], 32);
    ak[i] += __shfl_xor(ak[i], 16); ak[i] += __shfl_xor(ak[i], 32);
  }
  if (lane < 16){
    #pragma unroll
    for (int i = 0; i < 8; i++){
      nb[wv * 128 + m15 * 8 + i]       = aq[i];
      nb[512 + wv * 128 + m15 * 8 + i] = ak[i];
    }
  }
  __syncthreads();
  if (m0 == 0 && t < 128)
    nrm[(size_t)bh * 256 + n0 + t] = nb[t] + nb[128 + t] + nb[256 + t] + nb[384 + t];
  if (n0 == 0 && t >= 128){
    int m = t - 128;
    nrm[16384 + (size_t)bh * 256 + m0 + m] =
      nb[512 + m] + nb[640 + m] + nb[768 + m] + nb[896 + m];
  }

  #pragma unroll
  for (int mi = 0; mi < 4; mi++)
    #pragma unroll
    for (int ni = 0; ni < 4; ni++)
      #pragma unroll
      for (int r = 0; r < 4; r++){
        int nr = n0 + wm + mi * 16 + quad * 4 + r;
        int mc = m0 + wn + ni * 16 + m15;
        S[(size_t)bh * 65536 + (size_t)nr * 256 + mc] = acc[mi][ni][r];
      }
}

// ---------------------------------------------------------------------------
// K4: softmax_1 with l2-norm scaling + temperature (reads fused norms).
// ---------------------------------------------------------------------------
__global__ __launch_bounds__(256) void k_softmax(const float* __restrict__ S,
                                                 const float* __restrict__ nrm,
                                                 const float* __restrict__ temp,
                                                 unsigned short* __restrict__ P)
{
  const int t = threadIdx.x, lane = t & 63, wv = t >> 6;
  const int bh = blockIdx.y;
  const int n = blockIdx.x * 4 + wv;
  const float tp = temp[bh & 7];
  const size_t ro = (size_t)bh * 65536 + (size_t)n * 256;
  float4 sv = *(const float4*)(S + ro + lane * 4);
  float4 ka = *(const float4*)(nrm + 16384 + (size_t)bh * 256 + lane * 4);
  float nqv = nrm[(size_t)bh * 256 + n];
  float qi = tp / fmaxf(sqrtf(fmaxf(nqv, 0.f)), 1e-12f);
  float i0 = 1.f / fmaxf(sqrtf(fmaxf(ka.x, 0.f)), 1e-12f);
  float i1 = 1.f / fmaxf(sqrtf(fmaxf(ka.y, 0.f)), 1e-12f);
  float i2 = 1.f / fmaxf(sqrtf(fmaxf(ka.z, 0.f)), 1e-12f);
  float i3 = 1.f / fmaxf(sqrtf(fmaxf(ka.w, 0.f)), 1e-12f);
  float e0 = __expf(fminf(sv.x * qi * i0, 60.f));
  float e1 = __expf(fminf(sv.y * qi * i1, 60.f));
  float e2 = __expf(fminf(sv.z * qi * i2, 60.f));
  float e3 = __expf(fminf(sv.w * qi * i3, 60.f));
  float ss = e0 + e1 + e2 + e3;
  #pragma unroll
  for (int o = 32; o > 0; o >>= 1) ss += __shfl_xor(ss, o);
  float inv = 1.f / (ss + 1.f);
  uint2 pv;
  pv.x = (unsigned)f2bf(e0 * inv) | ((unsigned)f2bf(e1 * inv) << 16);
  pv.y = (unsigned)f2bf(e2 * inv) | ((unsigned)f2bf(e3 * inv) << 16);
  *(uint2*)(P + ro + lane * 4) = pv;
}

// ---------------------------------------------------------------------------
// K5: O[bh][d][n] = sum_m V[bh][d][m] * P[bh][n][m]. 128x128/block, grid(24,64).
// ---------------------------------------------------------------------------
__global__ __launch_bounds__(256) void k_ogemm(const unsigned short* __restrict__ Vd,
                                               const unsigned short* __restrict__ P,
                                               unsigned short* __restrict__ Od)
{
  __shared__ unsigned short sm[18432];
  unsigned short* const sa = sm;
  unsigned short* const sb = sm + 9216;
  const int t = threadIdx.x;
  const int bh = blockIdx.y;
  const int d0 = (blockIdx.x >> 1) << 7;
  const int n0 = (blockIdx.x & 1) << 7;
  const int lane = t & 63, wv = t >> 6;
  const int m15 = lane & 15, quad = lane >> 4;
  const int wm = (wv & 1) << 6, wn = (wv >> 1) << 6;
  f32x4 acc[4][4];
  f32x4 z = {0.f,0.f,0.f,0.f};
  #pragma unroll
  for (int i = 0; i < 4; i++)
    #pragma unroll
    for (int j = 0; j < 4; j++) acc[i][j] = z;

  for (int s = 0; s < 4; s++){
    __syncthreads();
    for (int j = t; j < 512; j += 256){
      int hf = j >> 8, jj = j & 255;
      int row = jj >> 1, hh = jj & 1;
      const unsigned short* src = hf
        ? (P  + (size_t)bh * 65536  + (size_t)(n0 + row) * 256 + s * 64 + hh * 32)
        : (Vd + (size_t)bh * 393216 + (size_t)(d0 + row) * 256 + s * 64 + hh * 32);
      uint4 v0 = *(const uint4*)src;
      uint4 v1 = *(const uint4*)(src + 8);
      uint4 v2 = *(const uint4*)(src + 16);
      uint4 v3 = *(const uint4*)(src + 24);
      unsigned* dst = (unsigned*)(hf ? sb : sa) + row * 36 + hh * 16;
      *(uint4*)dst        = v0;
      *(uint4*)(dst + 4)  = v1;
      *(uint4*)(dst + 8)  = v2;
      *(uint4*)(dst + 12) = v3;
    }
    __syncthreads();
    #pragma unroll
    for (int ks = 0; ks < 2; ks++){
      short8 afr[4], bfr[4];
      #pragma unroll
      for (int i = 0; i < 4; i++){
        afr[i] = *(const short8*)(sa + (wm + i * 16 + m15) * 72 + ks * 32 + quad * 8);
        bfr[i] = *(const short8*)(sb + (wn + i * 16 + m15) * 72 + ks * 32 + quad * 8);
      }
      #pragma unroll
      for (int mi = 0; mi < 4; mi++)
        #pragma unroll
        for (int ni = 0; ni < 4; ni++)
          acc[mi][ni] = __builtin_amdgcn_mfma_f32_16x16x32_bf16(afr[mi], bfr[ni], acc[mi][ni], 0, 0, 0);
    }
  }
  __syncthreads();
  #pragma unroll
  for (int mi = 0; mi < 4; mi++)
    #pragma unroll
    for (int ni = 0; ni < 4; ni++)
      #pragma unroll
      for (int r = 0; r < 4; r++)
        sm[(wm + mi * 16 + quad * 4 + r) * 136 + wn + ni * 16 + m15] = f2bf(acc[mi][ni][r]);
  __syncthreads();
  {
    int row = t >> 1, hh = t & 1;
    const unsigned short* lp = sm + row * 136 + hh * 64;
    unsigned short* gp = Od + (size_t)bh * 393216 + (size_t)(d0 + row) * 256 + n0 + hh * 64;
    #pragma unroll
    for (int u = 0; u < 8; u++)
      *(uint4*)(gp + u * 8) = *(const uint4*)(lp + u * 8);
  }
}

// ---------------------------------------------------------------------------
// K6: out[b][o][y][x] = sum_c48 wp[o][c] * Osp[b][c][y][x]. grid (16,16,8).
// ---------------------------------------------------------------------------
__global__ __launch_bounds__(256) void k_proj(const unsigned short* __restrict__ Od,
                                              const float* __restrict__ wp,
                                              float* __restrict__ out)
{
  __shared__ unsigned short sm6[21888];   // B[256][72]@0 + A[48][72]@18432; reuse lo fp32[16][264]
  unsigned short* const lb = sm6;
  unsigned short* const la = sm6 + 18432;
  float* const lo = (float*)sm6;
  const int t = threadIdx.x;
  const int w = blockIdx.x, h = blockIdx.y, b = blockIdx.z;
  for (int j = t; j < 10944; j += 256) ((unsigned*)sm6)[j] = 0u;
  __syncthreads();
  for (int j = t; j < 2304; j += 256){
    int m = j / 48, k = j - m * 48;
    la[m * 72 + k] = f2bf(wp[j]);
  }
  for (int j = t; j < 768; j += 256){
    int cp = j >> 5, nc = j & 31;
    int ch0 = 2 * cp;
    int head = ch0 / 6, cc = ch0 - head * 6;
    const unsigned short* r0 = Od + (((size_t)(b * 8 + head)) * 1536 + cc * 256 + h * 16 + w) * 256 + nc * 8;
    uint4 q0 = *(const uint4*)r0;
    uint4 q1 = *(const uint4*)(r0 + 65536);  // channel+1 = d+256 -> +65536 shorts
    const unsigned short* u0 = (const unsigned short*)&q0;
    const unsigned short* u1 = (const unsigned short*)&q1;
    unsigned* dst = (unsigned*)lb;
    int cx = (nc & 7) << 2;
    #pragma unroll
    for (int i = 0; i < 8; i++)
      dst[(nc * 8 + i) * 36 + (cp ^ cx)] = (unsigned)u0[i] | ((unsigned)u1[i] << 16);
  }
  __syncthreads();

  const int lane = t & 63, wv = t >> 6;
  const int m15 = lane & 15, quad = lane >> 4;
  const int n0w = wv << 6;
  f32x4 acc[3][4];
  f32x4 z = {0.f,0.f,0.f,0.f};
  #pragma unroll
  for (int i = 0; i < 3; i++)
    #pragma unroll
    for (int j = 0; j < 4; j++) acc[i][j] = z;
  #pragma unroll
  for (int ks = 0; ks < 2; ks++){
    short8 bfr[4];
    #pragma unroll
    for (int nt = 0; nt < 4; nt++){
      int rb = n0w + nt * 16 + m15;
      bfr[nt] = *(const short8*)(lb + rb * 72 + (((4 * ks + quad) ^ ((rb >> 3) & 7)) << 3));
    }
    #pragma unroll
    for (int mt = 0; mt < 3; mt++){
      short8 afr = *(const short8*)(la + (mt * 16 + m15) * 72 + ks * 32 + quad * 8);
      #pragma unroll
      for (int nt = 0; nt < 4; nt++)
        acc[mt][nt] = __builtin_amdgcn_mfma_f32_16x16x32_bf16(afr, bfr[nt], acc[mt][nt], 0, 0, 0);
    }
  }
  for (int mt = 0; mt < 3; mt++){
    __syncthreads();
    #pragma unroll
    for (int nt = 0; nt < 4; nt++)
      #pragma unroll
      for (int r = 0; r < 4; r++){
        int n = n0w + nt * 16 + m15;
        lo[(quad * 4 + r) * 264 + ((n & 0xF0) | ((n & 15) ^ (n >> 4)))] = acc[mt][nt][r];
      }
    __syncthreads();
    int fy = t >> 4, fx = t & 15;
    #pragma unroll
    for (int r = 0; r < 16; r++){
      float v = lo[r * 264 + fx * 16 + (fy ^ fx)];
      out[((size_t)(b * 48 + mt * 16 + r)) * 65536 + (h * 16 + fy) * 256 + w * 16 + fx] = v;
    }
  }
}

// ---------------------------------------------------------------------------
extern "C" void kernel_launch(void* const* d_in, const int* in_sizes, int n_in,
                              void* d_out, int out_size, void* d_ws, size_t ws_size,
                              hipStream_t stream)
{
  (void)in_sizes; (void)n_in; (void)out_size; (void)ws_size;
  const float* x  = (const float*)d_in[0];
  const float* wq = (const float*)d_in[1];
  const float* wd = (const float*)d_in[2];
  const float* wp = (const float*)d_in[3];
  const float* tp = (const float*)d_in[4];
  float* out = (float*)d_out;
  char* ws = (char*)d_ws;

  unsigned short* qkv = (unsigned short*)ws;                 // [0, 151 MB)
  unsigned short* Qd  = (unsigned short*)(ws + 150994944);   // tokens (contiguous Q,K,V)
  unsigned short* Kd  = (unsigned short*)(ws + 201326592);
  unsigned short* Vd  = (unsigned short*)(ws + 251658240);
  float*          S   = (float*)ws;                          // reuses qkv (dead after k_dw)
  unsigned short* P   = (unsigned short*)(ws + 16777216);
  float*          nrm = (float*)(ws + 301989888);            // [2][64][256] f32
  unsigned short* Od  = Qd;                                  // reuses Qd (dead after sgemm)

  k_qkv    <<<4096,              256, 0, stream>>>(x, wq, qkv);
  k_dw     <<<dim3(2, 16, 576),  512, 0, stream>>>(qkv, wd, Qd);
  k_sgemm  <<<dim3(4, 64),       256, 0, stream>>>(Qd, Kd, S, nrm);
  k_softmax<<<dim3(64, 64),      256, 0, stream>>>(S, nrm, tp, P);
  k_ogemm  <<<dim3(24, 64),      256, 0, stream>>>(Vd, P, Od);
  k_proj   <<<dim3(16, 16, 8),   256, 0, stream>>>(Od, wp, out);
}